// Round 3
// baseline (814.121 us; speedup 1.0000x reference)
//
#include <hip/hip_runtime.h>
#include <hip/hip_bf16.h>

#define D_DIM 1024
#define NITER 20
#define NBLK 32  // persistent sinkhorn blocks (each 1024 thr = 16 waves, 2 rows/wave)

typedef float f32x4 __attribute__((ext_vector_type(4)));
typedef __bf16 bf16x4 __attribute__((ext_vector_type(4)));
typedef __bf16 bf16x8 __attribute__((ext_vector_type(8)));

// ---- prep: M = exp(ls), Mt = M^T (tiled transpose); u = 1; cnt = 0 ----
__global__ __launch_bounds__(1024)
void prep_exp_transpose(const float* __restrict__ ls, float* __restrict__ Mm,
                        float* __restrict__ Mt, float* __restrict__ u,
                        unsigned* __restrict__ cnt) {
    __shared__ float tile[64][65];
    const int tx = threadIdx.x, ty = threadIdx.y;
    const int bx = blockIdx.x * 64, by = blockIdx.y * 64;
#pragma unroll
    for (int k = 0; k < 64; k += 16) {
        int r = by + ty + k, c = bx + tx;
        float v = expf(ls[r * D_DIM + c]);
        Mm[r * D_DIM + c] = v;
        tile[ty + k][tx] = v;
    }
    if (blockIdx.x == 0 && blockIdx.y == 0) {
        u[ty * 64 + tx] = 1.0f;
        if (tx == 0 && ty == 0) *cnt = 0u;  // reset barrier each replay
    }
    __syncthreads();
#pragma unroll
    for (int k = 0; k < 64; k += 16) {
        int r = bx + ty + k, c = by + tx;  // transposed block
        Mt[r * D_DIM + c] = tile[tx][ty + k];
    }
}

// ---- lightweight device-scope barrier: monotonic counter, thread-0 spin ----
__device__ inline void gbar(unsigned* cnt, unsigned& target) {
    __syncthreads();  // all waves' stores issued & drained (vmcnt0 at barrier)
    if (threadIdx.x == 0) {
        __threadfence();  // release (agent)
        __hip_atomic_fetch_add(cnt, 1u, __ATOMIC_ACQ_REL, __HIP_MEMORY_SCOPE_AGENT);
        target += NBLK;
        while (__hip_atomic_load(cnt, __ATOMIC_ACQUIRE, __HIP_MEMORY_SCOPE_AGENT) < target)
            __builtin_amdgcn_s_sleep(2);
        __threadfence();  // acquire (agent)
    }
    __syncthreads();
}

// ---- persistent Sinkhorn: 20 x { r = 1/(M u); bar; u = 1/(Mt r); bar } ----
// 32 blocks x 1024 thr; wave owns 2 rows held in registers. All cross-block
// data (r, u, cnt) moves ONLY via agent-scope atomics (coherent point); each
// block re-stages the 4 KB vector into LDS after every barrier.
__global__ __launch_bounds__(1024)
void sinkhorn_iters(const float* __restrict__ Mm, const float* __restrict__ Mt,
                    float* __restrict__ r, float* __restrict__ u,
                    unsigned* __restrict__ cnt) {
    __shared__ float vec[D_DIM];
    const int tid = threadIdx.x;
    const int wid = tid >> 6, lane = tid & 63;
    const int row0 = blockIdx.x * 32 + wid * 2;

    const f32x4* A0 = (const f32x4*)(Mm + (size_t)row0 * D_DIM);
    const f32x4* A1 = (const f32x4*)(Mm + (size_t)(row0 + 1) * D_DIM);
    const f32x4* T0 = (const f32x4*)(Mt + (size_t)row0 * D_DIM);
    const f32x4* T1 = (const f32x4*)(Mt + (size_t)(row0 + 1) * D_DIM);
    f32x4 a0[4], a1[4], t0[4], t1[4];
#pragma unroll
    for (int q = 0; q < 4; ++q) {
        a0[q] = A0[lane + q * 64]; a1[q] = A1[lane + q * 64];
        t0[q] = T0[lane + q * 64]; t1[q] = T1[lane + q * 64];
    }

    vec[tid] = u[tid];  // prep completed at launch boundary: plain load ok
    __syncthreads();

    unsigned target = 0;
    for (int it = 0; it < NITER; ++it) {
        // r = 1/(M u)
        float s0 = 0.f, s1 = 0.f;
#pragma unroll
        for (int q = 0; q < 4; ++q) {
            f32x4 b = ((const f32x4*)vec)[lane + q * 64];
            s0 += a0[q].x * b.x + a0[q].y * b.y + a0[q].z * b.z + a0[q].w * b.w;
            s1 += a1[q].x * b.x + a1[q].y * b.y + a1[q].z * b.z + a1[q].w * b.w;
        }
#pragma unroll
        for (int off = 32; off; off >>= 1) {
            s0 += __shfl_down(s0, off, 64);
            s1 += __shfl_down(s1, off, 64);
        }
        if (lane == 0) {
            __hip_atomic_store(&r[row0], 1.0f / s0, __ATOMIC_RELAXED, __HIP_MEMORY_SCOPE_AGENT);
            __hip_atomic_store(&r[row0 + 1], 1.0f / s1, __ATOMIC_RELAXED, __HIP_MEMORY_SCOPE_AGENT);
        }
        gbar(cnt, target);
        vec[tid] = __hip_atomic_load(&r[tid], __ATOMIC_RELAXED, __HIP_MEMORY_SCOPE_AGENT);
        __syncthreads();

        // u = 1/(Mt r)
        s0 = 0.f; s1 = 0.f;
#pragma unroll
        for (int q = 0; q < 4; ++q) {
            f32x4 b = ((const f32x4*)vec)[lane + q * 64];
            s0 += t0[q].x * b.x + t0[q].y * b.y + t0[q].z * b.z + t0[q].w * b.w;
            s1 += t1[q].x * b.x + t1[q].y * b.y + t1[q].z * b.z + t1[q].w * b.w;
        }
#pragma unroll
        for (int off = 32; off; off >>= 1) {
            s0 += __shfl_down(s0, off, 64);
            s1 += __shfl_down(s1, off, 64);
        }
        if (lane == 0) {
            __hip_atomic_store(&u[row0], 1.0f / s0, __ATOMIC_RELAXED, __HIP_MEMORY_SCOPE_AGENT);
            __hip_atomic_store(&u[row0 + 1], 1.0f / s1, __ATOMIC_RELAXED, __HIP_MEMORY_SCOPE_AGENT);
        }
        if (it < NITER - 1) {  // final visibility via kernel-completion flush
            gbar(cnt, target);
            vec[tid] = __hip_atomic_load(&u[tid], __ATOMIC_RELAXED, __HIP_MEMORY_SCOPE_AGENT);
            __syncthreads();
        }
    }
}

// ---- P_bf16[i][j] = bf16(M[i][j] * r[i] * u[j]) (GEMM's BT operand) ----
__global__ __launch_bounds__(256)
void finalize_P(const float* __restrict__ Mm, const float* __restrict__ r,
                const float* __restrict__ u, __bf16* __restrict__ P) {
    const int i = blockIdx.x;
    const int t = threadIdx.x;
    const float ri = r[i];
    f32x4 m = ((const f32x4*)(Mm + i * D_DIM))[t];
    f32x4 uu = ((const f32x4*)u)[t];
    bf16x4 o;
    o[0] = (__bf16)(m.x * ri * uu.x);
    o[1] = (__bf16)(m.y * ri * uu.y);
    o[2] = (__bf16)(m.z * ri * uu.z);
    o[3] = (__bf16)(m.w * ri * uu.w);
    ((bf16x4*)(P + i * D_DIM))[t] = o;
}

// ---- A (f32) -> Ab (bf16), grid-stride, 8 elems/thread ----
__global__ __launch_bounds__(256)
void convert_bf16(const float* __restrict__ A, __bf16* __restrict__ Ab, long n8) {
    const long stride = (long)gridDim.x * 256;
    for (long i = (long)blockIdx.x * 256 + threadIdx.x; i < n8; i += stride) {
        f32x4 v0 = ((const f32x4*)A)[2 * i];
        f32x4 v1 = ((const f32x4*)A)[2 * i + 1];
        bf16x8 o;
        o[0] = (__bf16)v0.x; o[1] = (__bf16)v0.y; o[2] = (__bf16)v0.z; o[3] = (__bf16)v0.w;
        o[4] = (__bf16)v1.x; o[5] = (__bf16)v1.y; o[6] = (__bf16)v1.z; o[7] = (__bf16)v1.w;
        ((bf16x8*)Ab)[i] = o;
    }
}

#define BM 128
#define BN 128
#define BK 32

// ---- fast GEMM: C = Ab (bf16) * Bt (bf16)^T — m97 structure: BOTH operands
// via global_load_lds(16B), linear LDS dest + pre-swizzled global source;
// XCD-grouped block decode (verified round 2: FETCH -4x, conflicts 0) ----
__global__ __launch_bounds__(256)
void gemm_bt16(const __bf16* __restrict__ A, const __bf16* __restrict__ Bt,
               float* __restrict__ C, int Msz, int Nsz, int Ksz) {
    __shared__ __bf16 As[BM * BK];  // 8 KB
    __shared__ __bf16 Bs[BN * BK];  // 8 KB
    const int tid = threadIdx.x;
    const int wave = tid >> 6, lane = tid & 63;
    const int wm = wave >> 1, wn = wave & 1;
    const int quad = lane >> 4, l16 = lane & 15;
    const int f = blockIdx.x;
    const int xcd = f & 7, s = f >> 3;
    const int m0 = (((s >> 3) << 3) | xcd) * BM;
    const int n0 = (s & 7) * BN;
    const int sR = (l16 >> 1) & 3;

    f32x4 acc[4][4] = {};

    for (int k0 = 0; k0 < Ksz; k0 += BK) {
        __syncthreads();
        // both operands: 16B/lane async, source chunk pre-swizzled
        // kb = (lane&3) ^ ((row>>1)&3), row = t8*16 + (lane>>2)
#pragma unroll
        for (int q = 0; q < 2; ++q) {
            int t8 = wave * 2 + q;
            int row = t8 * 16 + (lane >> 2);
            int kb = (lane & 3) ^ ((lane >> 3) & 3);
            const __bf16* ga = A + (size_t)(m0 + row) * Ksz + k0 + kb * 8;
            __builtin_amdgcn_global_load_lds(
                (const __attribute__((address_space(1))) void*)ga,
                (__attribute__((address_space(3))) void*)(As + t8 * 512), 16, 0, 0);
            const __bf16* gb = Bt + (size_t)(n0 + row) * Ksz + k0 + kb * 8;
            __builtin_amdgcn_global_load_lds(
                (const __attribute__((address_space(1))) void*)gb,
                (__attribute__((address_space(3))) void*)(Bs + t8 * 512), 16, 0, 0);
        }
        __syncthreads();  // vmcnt(0)+lgkmcnt(0) drain

        bf16x8 af[4], bfr[4];
#pragma unroll
        for (int a = 0; a < 4; ++a) {
            int arow = wm * 64 + a * 16 + l16;
            af[a] = *(const bf16x8*)(&As[arow * BK + (quad ^ sR) * 8]);
        }
#pragma unroll
        for (int b = 0; b < 4; ++b) {
            int brow = wn * 64 + b * 16 + l16;
            bfr[b] = *(const bf16x8*)(&Bs[brow * BK + (quad ^ sR) * 8]);
        }
#pragma unroll
        for (int a = 0; a < 4; ++a)
#pragma unroll
            for (int b = 0; b < 4; ++b)
                acc[a][b] = __builtin_amdgcn_mfma_f32_16x16x32_bf16(
                    af[a], bfr[b], acc[a][b], 0, 0, 0);
    }

#pragma unroll
    for (int a = 0; a < 4; ++a) {
        int mg = m0 + wm * 64 + a * 16 + quad * 4;
#pragma unroll
        for (int b = 0; b < 4; ++b) {
            int ng = n0 + wn * 64 + b * 16 + l16;
#pragma unroll
            for (int v = 0; v < 4; ++v)
                C[(size_t)(mg + v) * Nsz + ng] = acc[a][b][v];
        }
    }
}

// ---- fallback GEMM (round-2 verbatim): A f32, reg-staged + converted ----
__global__ __launch_bounds__(256)
void gemm_a32_bt16(const float* __restrict__ A, const __bf16* __restrict__ Bt,
                   float* __restrict__ C, int Msz, int Nsz, int Ksz) {
    __shared__ __bf16 As[BM * BK];
    __shared__ __bf16 Bs[BN * BK];
    const int tid = threadIdx.x;
    const int wave = tid >> 6, lane = tid & 63;
    const int wm = wave >> 1, wn = wave & 1;
    const int quad = lane >> 4, l16 = lane & 15;
    const int f = blockIdx.x;
    const int xcd = f & 7, s = f >> 3;
    const int m0 = (((s >> 3) << 3) | xcd) * BM;
    const int n0 = (s & 7) * BN;
    const int sR = (l16 >> 1) & 3;

    f32x4 acc[4][4] = {};

    for (int k0 = 0; k0 < Ksz; k0 += BK) {
        __syncthreads();
#pragma unroll
        for (int itc = 0; itc < 4; ++itc) {
            int idx = tid + itc * 256;
            int arow = idx >> 3, kq = idx & 7;
            f32x4 v = *(const f32x4*)(A + (size_t)(m0 + arow) * Ksz + k0 + kq * 4);
            bf16x4 b;
            b[0] = (__bf16)v.x; b[1] = (__bf16)v.y;
            b[2] = (__bf16)v.z; b[3] = (__bf16)v.w;
            int slot = (kq >> 1) ^ ((arow >> 1) & 3);
            *(bf16x4*)(&As[arow * BK + slot * 8 + (kq & 1) * 4]) = b;
        }
#pragma unroll
        for (int q = 0; q < 2; ++q) {
            int t8 = wave * 2 + q;
            int nrow = t8 * 16 + (lane >> 2);
            int kb = (lane & 3) ^ ((lane >> 3) & 3);
            const __bf16* g = Bt + (size_t)(n0 + nrow) * Ksz + k0 + kb * 8;
            __builtin_amdgcn_global_load_lds(
                (const __attribute__((address_space(1))) void*)g,
                (__attribute__((address_space(3))) void*)(Bs + t8 * 512), 16, 0, 0);
        }
        __syncthreads();

        bf16x8 af[4], bfr[4];
#pragma unroll
        for (int a = 0; a < 4; ++a) {
            int arow = wm * 64 + a * 16 + l16;
            af[a] = *(const bf16x8*)(&As[arow * BK + (quad ^ sR) * 8]);
        }
#pragma unroll
        for (int b = 0; b < 4; ++b) {
            int brow = wn * 64 + b * 16 + l16;
            bfr[b] = *(const bf16x8*)(&Bs[brow * BK + (quad ^ sR) * 8]);
        }
#pragma unroll
        for (int a = 0; a < 4; ++a)
#pragma unroll
            for (int b = 0; b < 4; ++b)
                acc[a][b] = __builtin_amdgcn_mfma_f32_16x16x32_bf16(
                    af[a], bfr[b], acc[a][b], 0, 0, 0);
    }

#pragma unroll
    for (int a = 0; a < 4; ++a) {
        int mg = m0 + wm * 64 + a * 16 + quad * 4;
#pragma unroll
        for (int b = 0; b < 4; ++b) {
            int ng = n0 + wn * 64 + b * 16 + l16;
#pragma unroll
            for (int v = 0; v < 4; ++v)
                C[(size_t)(mg + v) * Nsz + ng] = acc[a][b][v];
        }
    }
}

extern "C" void kernel_launch(void* const* d_in, const int* in_sizes, int n_in,
                              void* d_out, int out_size, void* d_ws, size_t ws_size,
                              hipStream_t stream) {
    const float* emb = (const float*)d_in[0];   // (B, 1024) f32
    const float* ls  = (const float*)d_in[1];   // (1024, 1024) f32
    float* out = (float*)d_out;                 // (B, 1024) f32
    char* ws = (char*)d_ws;

    float* Mm     = (float*)ws;                          // 4 MB
    float* Mt     = (float*)(ws + (4u << 20));           // 4 MB
    float* r      = (float*)(ws + (8u << 20));           // 4 KB
    float* u      = (float*)(ws + (8u << 20) + 4096);    // 4 KB
    unsigned* cnt = (unsigned*)(ws + (8u << 20) + 8192); // 128 B
    __bf16* P     = (__bf16*)(ws + (8u << 20) + 12288);  // 2 MB
    __bf16* Ab    = (__bf16*)(ws + (16u << 20));         // 128 MB (optional)

    const int Bv = in_sizes[0] / D_DIM;  // 65536
    const size_t need = (16u << 20) + (size_t)Bv * D_DIM * sizeof(__bf16);

    prep_exp_transpose<<<dim3(16, 16), dim3(64, 16), 0, stream>>>(ls, Mm, Mt, u, cnt);

    void* cargs[5];
    cargs[0] = (void*)&Mm; cargs[1] = (void*)&Mt;
    cargs[2] = (void*)&r;  cargs[3] = (void*)&u;
    cargs[4] = (void*)&cnt;
    hipLaunchCooperativeKernel(sinkhorn_iters, dim3(NBLK), dim3(1024), cargs, 0,
                               stream);

    finalize_P<<<D_DIM, 256, 0, stream>>>(Mm, r, u, P);

    if (ws_size >= need) {
        convert_bf16<<<2048, 256, 0, stream>>>(emb, Ab, (long)Bv * D_DIM / 8);
        gemm_bt16<<<dim3((Bv / BM) * (D_DIM / BN)), 256, 0, stream>>>(
            Ab, P, out, Bv, D_DIM, D_DIM);
    } else {
        gemm_a32_bt16<<<dim3((Bv / BM) * (D_DIM / BN)), 256, 0, stream>>>(
            emb, P, out, Bv, D_DIM, D_DIM);
    }
}

// Round 4
// 772.982 us; speedup vs baseline: 1.0532x; 1.0532x over previous
//
#include <hip/hip_runtime.h>
#include <hip/hip_bf16.h>

#define D_DIM 1024
#define NITER 20
#define NBLK 32  // persistent sinkhorn blocks (each 1024 thr = 16 waves, 2 rows/wave)

typedef float f32x4 __attribute__((ext_vector_type(4)));
typedef __bf16 bf16x4 __attribute__((ext_vector_type(4)));
typedef __bf16 bf16x8 __attribute__((ext_vector_type(8)));

// ---- prep: M = exp(ls), Mt = M^T (tiled transpose); u = 1; cnt = 0 ----
__global__ __launch_bounds__(1024)
void prep_exp_transpose(const float* __restrict__ ls, float* __restrict__ Mm,
                        float* __restrict__ Mt, float* __restrict__ u,
                        unsigned* __restrict__ cnt) {
    __shared__ float tile[64][65];
    const int tx = threadIdx.x, ty = threadIdx.y;
    const int bx = blockIdx.x * 64, by = blockIdx.y * 64;
#pragma unroll
    for (int k = 0; k < 64; k += 16) {
        int r = by + ty + k, c = bx + tx;
        float v = expf(ls[r * D_DIM + c]);
        Mm[r * D_DIM + c] = v;
        tile[ty + k][tx] = v;
    }
    if (blockIdx.x == 0 && blockIdx.y == 0) {
        u[ty * 64 + tx] = 1.0f;
        if (tx == 0 && ty == 0) *cnt = 0u;  // reset barrier each replay
    }
    __syncthreads();
#pragma unroll
    for (int k = 0; k < 64; k += 16) {
        int r = bx + ty + k, c = by + tx;  // transposed block
        Mt[r * D_DIM + c] = tile[tx][ty + k];
    }
}

// ---- lightweight barrier, NO cache-maintenance fences ----------------------
// All cross-block data moves via agent-scope atomics (coherence point, bypass
// non-coherent L1/XCD-L2), so no __threadfence (= L2 wb/inv, ~13us/barrier in
// round 3) is needed. RELEASE on the add orders this block's prior atomic
// stores (drained per-wave at __syncthreads) before the counter bump; the
// consumer's post-spin atomic loads issue in-order after the spin load.
__device__ inline void gbar(unsigned* cnt, unsigned& target) {
    __syncthreads();
    if (threadIdx.x == 0) {
        __hip_atomic_fetch_add(cnt, 1u, __ATOMIC_RELEASE, __HIP_MEMORY_SCOPE_AGENT);
        target += NBLK;
        while (__hip_atomic_load(cnt, __ATOMIC_RELAXED, __HIP_MEMORY_SCOPE_AGENT) < target)
            __builtin_amdgcn_s_sleep(2);
    }
    __syncthreads();
}

// ---- persistent Sinkhorn: 20 x { r = 1/(M u); bar; u = 1/(Mt r); bar } ----
__global__ __launch_bounds__(1024)
void sinkhorn_iters(const float* __restrict__ Mm, const float* __restrict__ Mt,
                    float* __restrict__ r, float* __restrict__ u,
                    unsigned* __restrict__ cnt) {
    __shared__ float vec[D_DIM];
    const int tid = threadIdx.x;
    const int wid = tid >> 6, lane = tid & 63;
    const int row0 = blockIdx.x * 32 + wid * 2;

    const f32x4* A0 = (const f32x4*)(Mm + (size_t)row0 * D_DIM);
    const f32x4* A1 = (const f32x4*)(Mm + (size_t)(row0 + 1) * D_DIM);
    const f32x4* T0 = (const f32x4*)(Mt + (size_t)row0 * D_DIM);
    const f32x4* T1 = (const f32x4*)(Mt + (size_t)(row0 + 1) * D_DIM);
    f32x4 a0[4], a1[4], t0[4], t1[4];
#pragma unroll
    for (int q = 0; q < 4; ++q) {
        a0[q] = A0[lane + q * 64]; a1[q] = A1[lane + q * 64];
        t0[q] = T0[lane + q * 64]; t1[q] = T1[lane + q * 64];
    }

    vec[tid] = u[tid];  // prep completed at launch boundary: plain load ok
    __syncthreads();

    unsigned target = 0;
    for (int it = 0; it < NITER; ++it) {
        // r = 1/(M u)
        float s0 = 0.f, s1 = 0.f;
#pragma unroll
        for (int q = 0; q < 4; ++q) {
            f32x4 b = ((const f32x4*)vec)[lane + q * 64];
            s0 += a0[q].x * b.x + a0[q].y * b.y + a0[q].z * b.z + a0[q].w * b.w;
            s1 += a1[q].x * b.x + a1[q].y * b.y + a1[q].z * b.z + a1[q].w * b.w;
        }
#pragma unroll
        for (int off = 32; off; off >>= 1) {
            s0 += __shfl_down(s0, off, 64);
            s1 += __shfl_down(s1, off, 64);
        }
        if (lane == 0) {
            __hip_atomic_store(&r[row0], 1.0f / s0, __ATOMIC_RELAXED, __HIP_MEMORY_SCOPE_AGENT);
            __hip_atomic_store(&r[row0 + 1], 1.0f / s1, __ATOMIC_RELAXED, __HIP_MEMORY_SCOPE_AGENT);
        }
        gbar(cnt, target);
        vec[tid] = __hip_atomic_load(&r[tid], __ATOMIC_RELAXED, __HIP_MEMORY_SCOPE_AGENT);
        __syncthreads();

        // u = 1/(Mt r)
        s0 = 0.f; s1 = 0.f;
#pragma unroll
        for (int q = 0; q < 4; ++q) {
            f32x4 b = ((const f32x4*)vec)[lane + q * 64];
            s0 += t0[q].x * b.x + t0[q].y * b.y + t0[q].z * b.z + t0[q].w * b.w;
            s1 += t1[q].x * b.x + t1[q].y * b.y + t1[q].z * b.z + t1[q].w * b.w;
        }
#pragma unroll
        for (int off = 32; off; off >>= 1) {
            s0 += __shfl_down(s0, off, 64);
            s1 += __shfl_down(s1, off, 64);
        }
        if (lane == 0) {
            __hip_atomic_store(&u[row0], 1.0f / s0, __ATOMIC_RELAXED, __HIP_MEMORY_SCOPE_AGENT);
            __hip_atomic_store(&u[row0 + 1], 1.0f / s1, __ATOMIC_RELAXED, __HIP_MEMORY_SCOPE_AGENT);
        }
        if (it < NITER - 1) {  // final visibility via kernel-completion flush
            gbar(cnt, target);
            vec[tid] = __hip_atomic_load(&u[tid], __ATOMIC_RELAXED, __HIP_MEMORY_SCOPE_AGENT);
            __syncthreads();
        }
    }
}

// ---- P_bf16[i][j] = bf16(M[i][j] * r[i] * u[j]) (GEMM's BT operand) ----
__global__ __launch_bounds__(256)
void finalize_P(const float* __restrict__ Mm, const float* __restrict__ r,
                const float* __restrict__ u, __bf16* __restrict__ P) {
    const int i = blockIdx.x;
    const int t = threadIdx.x;
    const float ri = r[i];
    f32x4 m = ((const f32x4*)(Mm + i * D_DIM))[t];
    f32x4 uu = ((const f32x4*)u)[t];
    bf16x4 o;
    o[0] = (__bf16)(m.x * ri * uu.x);
    o[1] = (__bf16)(m.y * ri * uu.y);
    o[2] = (__bf16)(m.z * ri * uu.z);
    o[3] = (__bf16)(m.w * ri * uu.w);
    ((bf16x4*)(P + i * D_DIM))[t] = o;
}

// ---- A (f32) -> Ab (bf16), grid-stride, 8 elems/thread ----
__global__ __launch_bounds__(256)
void convert_bf16(const float* __restrict__ A, __bf16* __restrict__ Ab, long n8) {
    const long stride = (long)gridDim.x * 256;
    for (long i = (long)blockIdx.x * 256 + threadIdx.x; i < n8; i += stride) {
        f32x4 v0 = ((const f32x4*)A)[2 * i];
        f32x4 v1 = ((const f32x4*)A)[2 * i + 1];
        bf16x8 o;
        o[0] = (__bf16)v0.x; o[1] = (__bf16)v0.y; o[2] = (__bf16)v0.z; o[3] = (__bf16)v0.w;
        o[4] = (__bf16)v1.x; o[5] = (__bf16)v1.y; o[6] = (__bf16)v1.z; o[7] = (__bf16)v1.w;
        ((bf16x8*)Ab)[i] = o;
    }
}

#define BM 128
#define BN 128
#define BK 32

// ---- fast GEMM: C = Ab (bf16) * Bt (bf16)^T — m97 structure (verified
// round 3: 226us, 607 TF). Unchanged this round for clean attribution. ----
__global__ __launch_bounds__(256)
void gemm_bt16(const __bf16* __restrict__ A, const __bf16* __restrict__ Bt,
               float* __restrict__ C, int Msz, int Nsz, int Ksz) {
    __shared__ __bf16 As[BM * BK];  // 8 KB
    __shared__ __bf16 Bs[BN * BK];  // 8 KB
    const int tid = threadIdx.x;
    const int wave = tid >> 6, lane = tid & 63;
    const int wm = wave >> 1, wn = wave & 1;
    const int quad = lane >> 4, l16 = lane & 15;
    const int f = blockIdx.x;
    const int xcd = f & 7, s = f >> 3;
    const int m0 = (((s >> 3) << 3) | xcd) * BM;
    const int n0 = (s & 7) * BN;
    const int sR = (l16 >> 1) & 3;

    f32x4 acc[4][4] = {};

    for (int k0 = 0; k0 < Ksz; k0 += BK) {
        __syncthreads();
        // both operands: 16B/lane async, source chunk pre-swizzled
        // kb = (lane&3) ^ ((row>>1)&3), row = t8*16 + (lane>>2)
#pragma unroll
        for (int q = 0; q < 2; ++q) {
            int t8 = wave * 2 + q;
            int row = t8 * 16 + (lane >> 2);
            int kb = (lane & 3) ^ ((lane >> 3) & 3);
            const __bf16* ga = A + (size_t)(m0 + row) * Ksz + k0 + kb * 8;
            __builtin_amdgcn_global_load_lds(
                (const __attribute__((address_space(1))) void*)ga,
                (__attribute__((address_space(3))) void*)(As + t8 * 512), 16, 0, 0);
            const __bf16* gb = Bt + (size_t)(n0 + row) * Ksz + k0 + kb * 8;
            __builtin_amdgcn_global_load_lds(
                (const __attribute__((address_space(1))) void*)gb,
                (__attribute__((address_space(3))) void*)(Bs + t8 * 512), 16, 0, 0);
        }
        __syncthreads();  // vmcnt(0)+lgkmcnt(0) drain

        bf16x8 af[4], bfr[4];
#pragma unroll
        for (int a = 0; a < 4; ++a) {
            int arow = wm * 64 + a * 16 + l16;
            af[a] = *(const bf16x8*)(&As[arow * BK + (quad ^ sR) * 8]);
        }
#pragma unroll
        for (int b = 0; b < 4; ++b) {
            int brow = wn * 64 + b * 16 + l16;
            bfr[b] = *(const bf16x8*)(&Bs[brow * BK + (quad ^ sR) * 8]);
        }
#pragma unroll
        for (int a = 0; a < 4; ++a)
#pragma unroll
            for (int b = 0; b < 4; ++b)
                acc[a][b] = __builtin_amdgcn_mfma_f32_16x16x32_bf16(
                    af[a], bfr[b], acc[a][b], 0, 0, 0);
    }

#pragma unroll
    for (int a = 0; a < 4; ++a) {
        int mg = m0 + wm * 64 + a * 16 + quad * 4;
#pragma unroll
        for (int b = 0; b < 4; ++b) {
            int ng = n0 + wn * 64 + b * 16 + l16;
#pragma unroll
            for (int v = 0; v < 4; ++v)
                C[(size_t)(mg + v) * Nsz + ng] = acc[a][b][v];
        }
    }
}

// ---- fallback GEMM (round-2 verbatim): A f32, reg-staged + converted ----
__global__ __launch_bounds__(256)
void gemm_a32_bt16(const float* __restrict__ A, const __bf16* __restrict__ Bt,
                   float* __restrict__ C, int Msz, int Nsz, int Ksz) {
    __shared__ __bf16 As[BM * BK];
    __shared__ __bf16 Bs[BN * BK];
    const int tid = threadIdx.x;
    const int wave = tid >> 6, lane = tid & 63;
    const int wm = wave >> 1, wn = wave & 1;
    const int quad = lane >> 4, l16 = lane & 15;
    const int f = blockIdx.x;
    const int xcd = f & 7, s = f >> 3;
    const int m0 = (((s >> 3) << 3) | xcd) * BM;
    const int n0 = (s & 7) * BN;
    const int sR = (l16 >> 1) & 3;

    f32x4 acc[4][4] = {};

    for (int k0 = 0; k0 < Ksz; k0 += BK) {
        __syncthreads();
#pragma unroll
        for (int itc = 0; itc < 4; ++itc) {
            int idx = tid + itc * 256;
            int arow = idx >> 3, kq = idx & 7;
            f32x4 v = *(const f32x4*)(A + (size_t)(m0 + arow) * Ksz + k0 + kq * 4);
            bf16x4 b;
            b[0] = (__bf16)v.x; b[1] = (__bf16)v.y;
            b[2] = (__bf16)v.z; b[3] = (__bf16)v.w;
            int slot = (kq >> 1) ^ ((arow >> 1) & 3);
            *(bf16x4*)(&As[arow * BK + slot * 8 + (kq & 1) * 4]) = b;
        }
#pragma unroll
        for (int q = 0; q < 2; ++q) {
            int t8 = wave * 2 + q;
            int nrow = t8 * 16 + (lane >> 2);
            int kb = (lane & 3) ^ ((lane >> 3) & 3);
            const __bf16* g = Bt + (size_t)(n0 + nrow) * Ksz + k0 + kb * 8;
            __builtin_amdgcn_global_load_lds(
                (const __attribute__((address_space(1))) void*)g,
                (__attribute__((address_space(3))) void*)(Bs + t8 * 512), 16, 0, 0);
        }
        __syncthreads();

        bf16x8 af[4], bfr[4];
#pragma unroll
        for (int a = 0; a < 4; ++a) {
            int arow = wm * 64 + a * 16 + l16;
            af[a] = *(const bf16x8*)(&As[arow * BK + (quad ^ sR) * 8]);
        }
#pragma unroll
        for (int b = 0; b < 4; ++b) {
            int brow = wn * 64 + b * 16 + l16;
            bfr[b] = *(const bf16x8*)(&Bs[brow * BK + (quad ^ sR) * 8]);
        }
#pragma unroll
        for (int a = 0; a < 4; ++a)
#pragma unroll
            for (int b = 0; b < 4; ++b)
                acc[a][b] = __builtin_amdgcn_mfma_f32_16x16x32_bf16(
                    af[a], bfr[b], acc[a][b], 0, 0, 0);
    }

#pragma unroll
    for (int a = 0; a < 4; ++a) {
        int mg = m0 + wm * 64 + a * 16 + quad * 4;
#pragma unroll
        for (int b = 0; b < 4; ++b) {
            int ng = n0 + wn * 64 + b * 16 + l16;
#pragma unroll
            for (int v = 0; v < 4; ++v)
                C[(size_t)(mg + v) * Nsz + ng] = acc[a][b][v];
        }
    }
}

extern "C" void kernel_launch(void* const* d_in, const int* in_sizes, int n_in,
                              void* d_out, int out_size, void* d_ws, size_t ws_size,
                              hipStream_t stream) {
    const float* emb = (const float*)d_in[0];   // (B, 1024) f32
    const float* ls  = (const float*)d_in[1];   // (1024, 1024) f32
    float* out = (float*)d_out;                 // (B, 1024) f32
    char* ws = (char*)d_ws;

    float* Mm     = (float*)ws;                          // 4 MB
    float* Mt     = (float*)(ws + (4u << 20));           // 4 MB
    float* r      = (float*)(ws + (8u << 20));           // 4 KB
    float* u      = (float*)(ws + (8u << 20) + 4096);    // 4 KB
    unsigned* cnt = (unsigned*)(ws + (8u << 20) + 8192); // 128 B
    __bf16* P     = (__bf16*)(ws + (8u << 20) + 12288);  // 2 MB
    __bf16* Ab    = (__bf16*)(ws + (16u << 20));         // 128 MB (optional)

    const int Bv = in_sizes[0] / D_DIM;  // 65536
    const size_t need = (16u << 20) + (size_t)Bv * D_DIM * sizeof(__bf16);

    prep_exp_transpose<<<dim3(16, 16), dim3(64, 16), 0, stream>>>(ls, Mm, Mt, u, cnt);

    void* cargs[5];
    cargs[0] = (void*)&Mm; cargs[1] = (void*)&Mt;
    cargs[2] = (void*)&r;  cargs[3] = (void*)&u;
    cargs[4] = (void*)&cnt;
    hipLaunchCooperativeKernel(sinkhorn_iters, dim3(NBLK), dim3(1024), cargs, 0,
                               stream);

    finalize_P<<<D_DIM, 256, 0, stream>>>(Mm, r, u, P);

    if (ws_size >= need) {
        convert_bf16<<<2048, 256, 0, stream>>>(emb, Ab, (long)Bv * D_DIM / 8);
        gemm_bt16<<<dim3((Bv / BM) * (D_DIM / BN)), 256, 0, stream>>>(
            Ab, P, out, Bv, D_DIM, D_DIM);
    } else {
        gemm_a32_bt16<<<dim3((Bv / BM) * (D_DIM / BN)), 256, 0, stream>>>(
            emb, P, out, Bv, D_DIM, D_DIM);
    }
}